// Round 3
// baseline (1103.612 us; speedup 1.0000x reference)
//
#include <hip/hip_runtime.h>

// DynamicUpsamplingFilter: per-pixel (3x25)@(25x16) matmul.
// x:      (3, 25, 128, 128)  fp32   (4.9 MB, L2/L3-cacheable, reused 25x)
// filt:   (25, 16, 25, 128, 128)    (65.5 MB, read exactly once -> nontemporal)
// out:    (48, 25, 128, 128)        (78.6 MB, written once -> nontemporal)
//
// 2 pixels per thread: shared 5x6 x-patch, 8B/lane filter loads/out stores
// (512 B per wave instruction). Memory-bound; compulsory traffic ~149 MB
// -> ~24 us floor at 6.3 TB/s.
//
// NOTE: __builtin_nontemporal_* requires a clang ext_vector_type, not HIP's
// class-based float2 (R2 compile failure).

#define T_ 25
#define H_ 128
#define W_ 128
#define C_ 3
#define U_ 16
#define KH_ 5
#define KW_ 5
#define HW_ (H_ * W_)       // 16384
#define THW_ (T_ * HW_)     // 409600

typedef float f32x2 __attribute__((ext_vector_type(2)));

__global__ __launch_bounds__(256) void duf_kernel(
    const float* __restrict__ x,
    const float* __restrict__ filt,
    float* __restrict__ out)
{
    const int pp = blockIdx.x * blockDim.x + threadIdx.x;  // pixel-pair id
    const int p0 = pp * 2;                                 // even pixel index
    const int t = p0 >> 14;            // /16384
    const int rem = p0 & (HW_ - 1);
    const int h = rem >> 7;            // /128
    const int w = rem & (W_ - 1);      // even, 0..126

    f32x2 acc[C_][U_];
#pragma unroll
    for (int c = 0; c < C_; ++c)
#pragma unroll
        for (int u = 0; u < U_; ++u) acc[c][u] = (f32x2)(0.f);

    const float* xt = x + (size_t)t * HW_;  // channel stride = THW_

#pragma unroll
    for (int a = 0; a < KH_; ++a) {
        const int hh = h + a - 2;
        const bool hok = (hh >= 0) & (hh < H_);
        // stage the 6-wide patch row for 3 channels (cols w-2 .. w+3)
        float xr[C_][KW_ + 1];
#pragma unroll
        for (int j = 0; j < KW_ + 1; ++j) {
            const int ww = w + j - 2;
            const bool ok = hok & (ww >= 0) & (ww < W_);
            const int xoff = hh * W_ + ww;
#pragma unroll
            for (int c = 0; c < C_; ++c)
                xr[c][j] = ok ? xt[(size_t)c * THW_ + xoff] : 0.f;
        }
#pragma unroll
        for (int b = 0; b < KW_; ++b) {
            const int k = a * KW_ + b;
            const f32x2* fp = (const f32x2*)(filt + (size_t)k * U_ * THW_ + p0);
#pragma unroll
            for (int u = 0; u < U_; ++u) {
                const f32x2 f = __builtin_nontemporal_load(fp + (size_t)u * (THW_ / 2));
#pragma unroll
                for (int c = 0; c < C_; ++c) {
                    acc[c][u].x += xr[c][b] * f.x;
                    acc[c][u].y += xr[c][b + 1] * f.y;
                }
            }
        }
    }

#pragma unroll
    for (int c = 0; c < C_; ++c)
#pragma unroll
        for (int u = 0; u < U_; ++u)
            __builtin_nontemporal_store(
                acc[c][u],
                (f32x2*)(out + (size_t)(c * U_ + u) * THW_ + p0));
}

extern "C" void kernel_launch(void* const* d_in, const int* in_sizes, int n_in,
                              void* d_out, int out_size, void* d_ws, size_t ws_size,
                              hipStream_t stream) {
    const float* x = (const float*)d_in[0];
    const float* filt = (const float*)d_in[1];
    float* out = (float*)d_out;
    dim3 grid((THW_ / 2) / 256);  // 800 blocks, exact
    dim3 block(256);
    duf_kernel<<<grid, block, 0, stream>>>(x, filt, out);
}